// Round 15
// baseline (231.418 us; speedup 1.0000x reference)
//
#include <hip/hip_runtime.h>
#include <cfloat>

typedef unsigned short u16;
typedef unsigned int u32;
typedef __bf16 v8bf16 __attribute__((ext_vector_type(8)));
typedef float v4f32 __attribute__((ext_vector_type(4)));
typedef float v16f32 __attribute__((ext_vector_type(16)));

#define MPAD 4224            // 4097 keys padded to 66*64
// sqrt(1/8) * sqrt(log2(e)) : folds head-scale AND base-2 softmax into q and k
#define QKS 0.42466090f
#define GRPS 1024            // waves per split: (16 bh) * (16 qt) * (4 w)

__device__ __forceinline__ u16 f2bf(float f) {
  union { float f; u32 u; } v; v.f = f;
  u32 u = v.u;
  u32 r = (u + 0x7FFFu + ((u >> 16) & 1u)) >> 16;
  return (u16)r;
}

// pack two f32 -> one u32 holding (bf16(hi)<<16)|bf16(lo), truncating
__device__ __forceinline__ u32 pkbf(float lo, float hi) {
  union { float f; u32 u; } a, c;
  a.f = lo; c.f = hi;
  return __builtin_amdgcn_perm(c.u, a.u, 0x07060302);
}

__device__ __forceinline__ float asf(u32 u) {
  union { u32 u; float f; } v; v.u = u; return v.f;
}

// exp2 + row-sum + bf16 pack for one q-group (both kc halves).
// Half-wave exchange via v_permlane32_swap_b32 (R1/R8-proven).
__device__ __forceinline__ void exppack2(v16f32& sA, v16f32& sB, float& lst,
                                         v8bf16 pf[4]) {
  float rsum = 0.f;
#pragma unroll
  for (int i = 0; i < 16; i++) { float p = __builtin_amdgcn_exp2f(sA[i]); sA[i] = p; rsum += p; }
#pragma unroll
  for (int i = 0; i < 16; i++) { float p = __builtin_amdgcn_exp2f(sB[i]); sB[i] = p; rsum += p; }
  float a2 = rsum, b2 = rsum;
  asm("v_permlane32_swap_b32 %0, %1" : "+v"(a2), "+v"(b2));
  lst += a2 + b2;   // own + partner (lane^32)
#pragma unroll
  for (int kc = 0; kc < 2; kc++) {
    v16f32& s = kc ? sB : sA;
#pragma unroll
    for (int s16 = 0; s16 < 2; s16++) {
      u32 w0 = pkbf(s[s16 * 8 + 0], s[s16 * 8 + 1]);
      u32 w1 = pkbf(s[s16 * 8 + 2], s[s16 * 8 + 3]);
      u32 w2 = pkbf(s[s16 * 8 + 4], s[s16 * 8 + 5]);
      u32 w3 = pkbf(s[s16 * 8 + 6], s[s16 * 8 + 7]);
      asm("v_permlane32_swap_b32 %0, %1" : "+v"(w0), "+v"(w2));
      asm("v_permlane32_swap_b32 %0, %1" : "+v"(w1), "+v"(w3));
      union { u32 u[4]; v8bf16 v; } pu;
      pu.u[0] = w0; pu.u[1] = w1; pu.u[2] = w2; pu.u[3] = w3;
      pf[kc * 2 + s16] = pu.v;
    }
  }
}

// ================= prep_all: 4 independent prep stages in ONE launch ===============
__global__ __launch_bounds__(256) void prep_all(
    const void* __restrict__ mask, float* __restrict__ mp,
    const float* __restrict__ Wq, const float* __restrict__ Wkv,
    const float* __restrict__ Wo, u16* __restrict__ WqT,
    u16* __restrict__ WkvT, u16* __restrict__ WoT,
    const float* __restrict__ x, const float* __restrict__ g,
    u16* __restrict__ xn, const float4* __restrict__ ctx, u16* __restrict__ cb,
    const float* __restrict__ nullkv, u16* __restrict__ KVt) {
  int bb = blockIdx.x;
  int tid = threadIdx.x;
  if (bb < 33) {
    __shared__ int sflag;
    if (tid == 0) sflag = 0;
    __syncthreads();
    const unsigned char* mb = (const unsigned char*)mask;
    int loc = 0;
#pragma unroll
    for (int k = 0; k < 32; k++) {
      int i = tid * 32 + k;
      if ((i & 3) && mb[i]) loc = 1;
    }
    if (loc) sflag = 1;
    __syncthreads();
    int isbyte = sflag;
    int i = bb * 256 + tid;
    if (i >= 2 * MPAD) return;
    int b = i / MPAD, p = i - b * MPAD;
    float v;
    if (p == 0) v = 0.f;
    else if (p <= 4096) {
      int j = b * 4096 + (p - 1);
      int on = isbyte ? (((const unsigned char*)mask)[j] != 0)
                      : (((const int*)mask)[j] != 0);
      v = on ? 0.f : -1e38f;
    } else v = -1e38f;
    mp[i] = v;
  } else if (bb < 1057) {
    __shared__ float tile[32][33];
    int t = bb - 33;
    const float* in; u16* out; int N; float scale; int base;
    if (t < 256)      { in = Wq;  out = WqT;  N = 512;  scale = QKS; base = t; }
    else if (t < 768) { in = Wkv; out = WkvT; N = 1024; scale = 1.f; base = t - 256; }
    else              { in = Wo;  out = WoT;  N = 512;  scale = 1.f; base = t - 768; }
    const int K = 512;
    int ntiles = N >> 5;
    int bx = base % ntiles, by = base / ntiles;
    int n0 = bx * 32, k0 = by * 32;
    int c = tid & 31, r8 = tid >> 5;
#pragma unroll
    for (int i = 0; i < 4; i++) {
      int r = r8 + i * 8;
      tile[r][c] = in[(size_t)(k0 + r) * N + n0 + c];
    }
    __syncthreads();
#pragma unroll
    for (int i = 0; i < 4; i++) {
      int r = r8 + i * 8;
      out[(size_t)(n0 + r) * K + k0 + c] = f2bf(tile[c][r] * scale);
    }
  } else if (bb < 7201) {
    int local = bb - 1057;
    if (local < 2048) {
      int lane = tid & 63, w = tid >> 6;
      int row = local * 4 + w;
      const float* p = x + (size_t)row * 512 + lane * 8;
      float4 f0 = *(const float4*)p;
      float4 f1 = *(const float4*)(p + 4);
      float v[8] = {f0.x, f0.y, f0.z, f0.w, f1.x, f1.y, f1.z, f1.w};
      float sum = 0.f, sq = 0.f;
#pragma unroll
      for (int i = 0; i < 8; i++) { sum += v[i]; sq += v[i] * v[i]; }
#pragma unroll
      for (int m = 1; m < 64; m <<= 1) { sum += __shfl_xor(sum, m); sq += __shfl_xor(sq, m); }
      float mean = sum * (1.f / 512.f);
      float var = sq * (1.f / 512.f) - mean * mean;
      float rstd = rsqrtf(var + 1e-5f);
      const float* gp = g + lane * 8;
      u16 o[8];
#pragma unroll
      for (int i = 0; i < 8; i++) o[i] = f2bf((v[i] - mean) * rstd * gp[i]);
      *(uint4*)&xn[(size_t)row * 512 + lane * 8] = *(uint4*)o;
    } else {
      int i = (local - 2048) * 256 + tid;
      float4 f = ctx[i];
      u16 o[4] = {f2bf(f.x), f2bf(f.y), f2bf(f.z), f2bf(f.w)};
      *(uint2*)&cb[(size_t)i * 4] = *(uint2*)o;
    }
  } else {
    int bh = bb - 7201;
    size_t tb64 = ((size_t)bh * 66 + 64) * 8192;
    uint4 z = make_uint4(0, 0, 0, 0);
    for (int i = tid; i < 2048; i += 256)
      *(uint4*)&KVt[tb64 + (size_t)i * 8] = z;
    size_t tb0 = (size_t)bh * 66 * 8192;
    if (tid < 64) {
      int d = tid;
      KVt[tb0 + (size_t)(d >> 3) * 512 + (d & 7)] = f2bf(nullkv[d] * QKS);
      KVt[tb0 + 4096 + (size_t)d * 8] = f2bf(nullkv[64 + d]);
    }
  }
}

// ---------------- bf16 MFMA GEMM core (m97-structure, R8-proven) -------------------
__device__ __forceinline__ void gemm_core(const u16* __restrict__ A,
    const u16* __restrict__ Bt, u16* __restrict__ outb,
    u16* __restrict__ KVt, int Ncols, int mode, int bidx,
    u16* As /*128*32*/, u16* Bs /*128*32*/) {
  int tiles_n = Ncols >> 7;
  int n0 = (bidx % tiles_n) * 128;
  int m0 = (bidx / tiles_n) * 128;
  int tid = threadIdx.x;
  int lane = tid & 63, w = tid >> 6, quad = lane >> 4, l15 = lane & 15;
  int wr = w >> 1, wc = w & 1;
  int srow = tid >> 2, scol = (tid & 3) * 8;
  v4f32 acc[4][4];
#pragma unroll
  for (int i = 0; i < 4; i++)
#pragma unroll
    for (int j = 0; j < 4; j++) acc[i][j] = (v4f32){0.f, 0.f, 0.f, 0.f};

  for (int k0 = 0; k0 < 512; k0 += 32) {
    __syncthreads();
    __builtin_amdgcn_global_load_lds((const u32*)&A[(size_t)(m0 + srow) * 512 + k0 + scol],
                                     (u32*)&As[tid * 8], 16, 0, 0);
    __builtin_amdgcn_global_load_lds((const u32*)&A[(size_t)(m0 + 64 + srow) * 512 + k0 + scol],
                                     (u32*)&As[64 * 32 + tid * 8], 16, 0, 0);
    __builtin_amdgcn_global_load_lds((const u32*)&Bt[(size_t)(n0 + srow) * 512 + k0 + scol],
                                     (u32*)&Bs[tid * 8], 16, 0, 0);
    __builtin_amdgcn_global_load_lds((const u32*)&Bt[(size_t)(n0 + 64 + srow) * 512 + k0 + scol],
                                     (u32*)&Bs[64 * 32 + tid * 8], 16, 0, 0);
    __syncthreads();
    v8bf16 af[4], bf[4];
#pragma unroll
    for (int i = 0; i < 4; i++)
      af[i] = *(const v8bf16*)&As[(wr * 64 + i * 16 + l15) * 32 + quad * 8];
#pragma unroll
    for (int j = 0; j < 4; j++)
      bf[j] = *(const v8bf16*)&Bs[(wc * 64 + j * 16 + l15) * 32 + quad * 8];
#pragma unroll
    for (int i = 0; i < 4; i++)
#pragma unroll
      for (int j = 0; j < 4; j++)
        acc[i][j] = __builtin_amdgcn_mfma_f32_16x16x32_bf16(af[i], bf[j], acc[i][j], 0, 0, 0);
  }
#pragma unroll
  for (int i = 0; i < 4; i++) {
    int rbase = m0 + wr * 64 + i * 16 + quad * 4;
#pragma unroll
    for (int j = 0; j < 4; j++) {
      int col = n0 + wc * 64 + j * 16 + l15;
#pragma unroll
      for (int r = 0; r < 4; r++) {
        float v = acc[i][j][r];
        int row = rbase + r;
        if (mode == 0) {
          outb[(size_t)row * 512 + col] = f2bf(v);
        } else {
          int b2 = row >> 12, mr = row & 4095;
          int kk = mr + 1, kt = kk >> 6, kl = kk & 63;
          int kvsel = col >> 9, hh = (col >> 6) & 7, d = col & 63;
          size_t tb = ((size_t)(b2 * 8 + hh) * 66 + kt) * 8192;
          if (kvsel == 0) {
            int chunk = (((d >> 4) * 2 + ((d >> 3) & 1)) * 2 + (kl >> 5)) * 32 + (kl & 31);
            KVt[tb + (size_t)chunk * 8 + (d & 7)] = f2bf(v * QKS);
          } else {
            int chunk = (((kl >> 4) * 2 + ((kl >> 3) & 1)) * 2 + (d >> 5)) * 32 + (d & 31);
            KVt[tb + 4096 + (size_t)chunk * 8 + (kl & 7)] = f2bf(v);
          }
        }
      }
    }
  }
}

// q-proj (bid 0..255) and kv-proj (bid 256..767) in ONE launch, XCD-swizzled
// (R14 A/B: swizzle neutral, kept as harmless)
__global__ __launch_bounds__(256) void gemm_qkv(const u16* __restrict__ xn,
    const u16* __restrict__ WqT, u16* __restrict__ qb,
    const u16* __restrict__ cb, const u16* __restrict__ WkvT,
    u16* __restrict__ KVt) {
  __shared__ __attribute__((aligned(16))) u16 As[128 * 32];
  __shared__ __attribute__((aligned(16))) u16 Bs[128 * 32];
  int obid = blockIdx.x;
  int bb = (obid & 7) * 96 + (obid >> 3);   // bijective over 0..767
  if (bb < 256) gemm_core(xn, WqT, qb, nullptr, 512, 0, bb, As, Bs);
  else          gemm_core(cb, WkvT, nullptr, KVt, 1024, 1, bb - 256, As, Bs);
}

// ---------------- flash attention v16 (R10-proven: R8 body + setprio) ----------------
__global__ __launch_bounds__(256, 2) void attn_kernel(const u16* __restrict__ q,
    const u16* __restrict__ KVt, const float* __restrict__ maskbias,
    u32* __restrict__ Opart, float* __restrict__ lbuf) {
  int obid = blockIdx.x;
  int bid = (obid & 7) * 64 + (obid >> 3);   // 512 = 8 XCDs * 64: bijective
  int qt = bid & 15, bhs = bid >> 4;
  int s_p = bhs & 1, bh = bhs >> 1;
  int b = bh >> 3, hh = bh & 7;
  int tid = threadIdx.x, lane = tid & 63, w = tid >> 6;
  int m31 = lane & 31, h = (lane >> 5) & 1;
  int grp = (bh * 16 + qt) * 4 + w;
  int q0 = qt * 256 + w * 64;

  v8bf16 qf[2][4];
#pragma unroll
  for (int qg = 0; qg < 2; qg++) {
    const u16* qp = q + (size_t)(b * 4096 + q0 + qg * 32 + m31) * 512 + hh * 64 + h * 8;
#pragma unroll
    for (int ks = 0; ks < 4; ks++) qf[qg][ks] = *(const v8bf16*)&qp[ks * 16];
  }

  v16f32 acc[2][2];
#pragma unroll
  for (int qg = 0; qg < 2; qg++)
#pragma unroll
    for (int db = 0; db < 2; db++)
#pragma unroll
      for (int i = 0; i < 16; i++) acc[qg][db][i] = 0.f;
  float l_st[2] = {0.f, 0.f};

  const u16* kvb = KVt + (size_t)bh * 66 * 8192 + (size_t)(h * 64 + m31) * 8;
  const float* mg = maskbias + b * MPAD;
  int kt0 = s_p * 33;

  for (int kt = kt0; kt < kt0 + 33; ++kt) {
    const u16* tb = kvb + (size_t)kt * 8192;
    v8bf16 kf[4][2];
#pragma unroll
    for (int ks = 0; ks < 4; ks++)
#pragma unroll
      for (int kc = 0; kc < 2; kc++)
        kf[ks][kc] = *(const v8bf16*)&tb[ks * 1024 + kc * 256];
    v16f32 bias_s[2];
#pragma unroll
    for (int kc = 0; kc < 2; kc++)
#pragma unroll
      for (int gg = 0; gg < 4; gg++) {
        float4 bv = *(const float4*)&mg[kt * 64 + kc * 32 + gg * 8 + h * 4];
        bias_s[kc][gg * 4 + 0] = bv.x;
        bias_s[kc][gg * 4 + 1] = bv.y;
        bias_s[kc][gg * 4 + 2] = bv.z;
        bias_s[kc][gg * 4 + 3] = bv.w;
      }

    v8bf16 pf[2][4];
    {
      v16f32 s0 = bias_s[0], s1 = bias_s[1];
      __builtin_amdgcn_s_setprio(1);
#pragma unroll
      for (int ks = 0; ks < 4; ks++) {
        s0 = __builtin_amdgcn_mfma_f32_32x32x16_bf16(kf[ks][0], qf[0][ks], s0, 0, 0, 0);
        s1 = __builtin_amdgcn_mfma_f32_32x32x16_bf16(kf[ks][1], qf[0][ks], s1, 0, 0, 0);
      }
      __builtin_amdgcn_s_setprio(0);
      exppack2(s0, s1, l_st[0], pf[0]);
    }
    __builtin_amdgcn_s_setprio(1);
#pragma unroll
    for (int ks = 0; ks < 4; ks++) {
      bias_s[0] = __builtin_amdgcn_mfma_f32_32x32x16_bf16(kf[ks][0], qf[1][ks], bias_s[0], 0, 0, 0);
      bias_s[1] = __builtin_amdgcn_mfma_f32_32x32x16_bf16(kf[ks][1], qf[1][ks], bias_s[1], 0, 0, 0);
    }
    __builtin_amdgcn_s_setprio(0);
    exppack2(bias_s[0], bias_s[1], l_st[1], pf[1]);

    v8bf16 vf[4][2];
#pragma unroll
    for (int jb = 0; jb < 4; jb++)
#pragma unroll
      for (int db = 0; db < 2; db++)
        vf[jb][db] = *(const v8bf16*)&tb[4096 + jb * 1024 + db * 256];

    __builtin_amdgcn_s_setprio(1);
#pragma unroll
    for (int qg = 0; qg < 2; qg++)
#pragma unroll
      for (int jb = 0; jb < 4; jb++)
#pragma unroll
        for (int db = 0; db < 2; db++)
          acc[qg][db] = __builtin_amdgcn_mfma_f32_32x32x16_bf16(vf[jb][db], pf[qg][jb], acc[qg][db], 0, 0, 0);
    __builtin_amdgcn_s_setprio(0);
  }

  size_t ob = (size_t)(s_p * GRPS + grp) * 2048;
#pragma unroll
  for (int qg = 0; qg < 2; qg++)
#pragma unroll
    for (int db = 0; db < 2; db++)
#pragma unroll
      for (int rp = 0; rp < 8; rp++)
        Opart[ob + qg * 1024 + (size_t)(db * 8 + rp) * 64 + lane] =
            pkbf(acc[qg][db][2 * rp], acc[qg][db][2 * rp + 1]);
  if (h == 0) {
    lbuf[(size_t)(s_p * GRPS + grp) * 64 + m31] = l_st[0];
    lbuf[(size_t)(s_p * GRPS + grp) * 64 + 32 + m31] = l_st[1];
  }
}

// ============ tail3 v4: 512 blocks x 16-row panels (2 blocks/CU overlap) ============
// bid = ((((b*16+qt)*4+w)*2+qg)<<1)|h16. Block owns rows [h16*16, h16*16+16) of its
// (qg) 32-row group x all 512 cols.
// Stage 1: lanes remapped (rr=lane&15, hsel=(lane>>4)&1, dup=lane>>5; rp=dup*4+rpi)
//   so the 64 lanes x 8 iters load exactly the 512 Opart words of this 16-row slice
//   once each (bijection onto v2's formula). As[16][520].
// Stage 2: af broadcast (all waves same 16 rows); waves split cols 4-way (acc[8]).
// Stage 3: LN via l15-shfl + part[4][16][2] cross-wave table.
// LDS 16.6+32+0.5 = 49.2 KB -> 2 blocks/CU co-resident; combine||GEMM overlap.
__global__ __launch_bounds__(256) void tail3(const u32* __restrict__ Opart,
    const float* __restrict__ lbuf, const u16* __restrict__ WoT,
    const float* __restrict__ g, float* __restrict__ out) {
  __shared__ __attribute__((aligned(16))) u16 As[16 * 520];   // 16640 B
  __shared__ __attribute__((aligned(16))) u16 Bs[512 * 32];   // 32768 B
  __shared__ float part[4][16][2];                            // 512 B
  int bid = blockIdx.x;
  int tid = threadIdx.x;
  int w4 = tid >> 6, lane = tid & 63;
  int h16 = bid & 1, qg = (bid >> 1) & 1, w = (bid >> 2) & 3;
  int qt = (bid >> 4) & 15, b = bid >> 8;
  size_t rowbase = (size_t)b * 4096 + qt * 256 + w * 64 + qg * 32 + h16 * 16;

  // ---- stage 1: combine the 16-row slice of 8 units into As (2 units/wave)
  {
    int rr = lane & 15, hsel = (lane >> 4) & 1, dup = lane >> 5;
    int srcl = hsel * 32 + h16 * 16 + rr;     // lane index in Opart's 64-wide layout
#pragma unroll
    for (int i = 0; i < 2; i++) {
      int hh = i * 4 + w4;
      int grp = (b * 8 + hh) * 64 + qt * 4 + w;
      float l0 = lbuf[(size_t)grp * 64 + qg * 32 + h16 * 16 + rr];
      float l1 = lbuf[(size_t)(GRPS + grp) * 64 + qg * 32 + h16 * 16 + rr];
      float inv = 1.f / (l0 + l1);
#pragma unroll
      for (int db = 0; db < 2; db++)
#pragma unroll
        for (int rpi = 0; rpi < 4; rpi++) {
          int rp = dup * 4 + rpi;
          u32 a = Opart[(size_t)grp * 2048 + qg * 1024 + (db * 8 + rp) * 64 + srcl];
          u32 c = Opart[(size_t)(GRPS + grp) * 2048 + qg * 1024 + (db * 8 + rp) * 64 + srcl];
          float fe = (asf(a << 16) + asf(c << 16)) * inv;
          float fo = (asf(a & 0xFFFF0000u) + asf(c & 0xFFFF0000u)) * inv;
          int reg = 2 * rp;
          int d0 = (reg & 3) + 8 * (reg >> 2) + 4 * hsel + 32 * db;
          *(u32*)&As[rr * 520 + hh * 64 + d0] = pkbf(fe, fo);
        }
    }
  }

  // ---- stage 2: GEMM (16x512) = As x WoT^T; wave w4 owns cols w4*128..+128
  int quad = lane >> 4, l15 = lane & 15;
  int srow = tid >> 2, scol = (tid & 3) * 8;
  v4f32 acc[8];
#pragma unroll
  for (int j = 0; j < 8; j++) acc[j] = (v4f32){0.f, 0.f, 0.f, 0.f};

  for (int k0 = 0; k0 < 512; k0 += 32) {
    __syncthreads();   // first iter: also guards As writes
#pragma unroll
    for (int v = 0; v < 8; v++)
      __builtin_amdgcn_global_load_lds((const u32*)&WoT[(size_t)(v * 64 + srow) * 512 + k0 + scol],
                                       (u32*)&Bs[(size_t)v * 2048 + tid * 8], 16, 0, 0);
    __syncthreads();
    v8bf16 af = *(const v8bf16*)&As[l15 * 520 + k0 + quad * 8];
#pragma unroll
    for (int j = 0; j < 8; j++) {
      v8bf16 bf = *(const v8bf16*)&Bs[(w4 * 128 + j * 16 + l15) * 32 + quad * 8];
      acc[j] = __builtin_amdgcn_mfma_f32_16x16x32_bf16(af, bf, acc[j], 0, 0, 0);
    }
  }

  // ---- stage 3: LN. lane holds rows quad*4+r, cols w4*128 + j*16+l15.
  float rs[4] = {0.f, 0.f, 0.f, 0.f}, sq[4] = {0.f, 0.f, 0.f, 0.f};
#pragma unroll
  for (int j = 0; j < 8; j++)
#pragma unroll
    for (int r = 0; r < 4; r++) { float v = acc[j][r]; rs[r] += v; sq[r] += v * v; }
#pragma unroll
  for (int m = 1; m < 16; m <<= 1)
#pragma unroll
    for (int r = 0; r < 4; r++) { rs[r] += __shfl_xor(rs[r], m); sq[r] += __shfl_xor(sq[r], m); }
  if (l15 == 0) {
#pragma unroll
    for (int r = 0; r < 4; r++) {
      part[w4][quad * 4 + r][0] = rs[r];
      part[w4][quad * 4 + r][1] = sq[r];
    }
  }
  __syncthreads();
  float mean[4], rstd[4];
#pragma unroll
  for (int r = 0; r < 4; r++) {
    int rl = quad * 4 + r;
    float trs = part[0][rl][0] + part[1][rl][0] + part[2][rl][0] + part[3][rl][0];
    float tsq = part[0][rl][1] + part[1][rl][1] + part[2][rl][1] + part[3][rl][1];
    mean[r] = trs * (1.f / 512.f);
    float var = tsq * (1.f / 512.f) - mean[r] * mean[r];
    rstd[r] = rsqrtf(var + 1e-5f);
  }
#pragma unroll
  for (int j = 0; j < 8; j++) {
    float gv = g[w4 * 128 + j * 16 + l15];
#pragma unroll
    for (int r = 0; r < 4; r++) {
      size_t row = rowbase + quad * 4 + r;
      out[row * 512 + w4 * 128 + j * 16 + l15] = (acc[j][r] - mean[r]) * rstd[r] * gv;
    }
  }
}

// =======================================================================
extern "C" void kernel_launch(void* const* d_in, const int* in_sizes, int n_in,
                              void* d_out, int out_size, void* d_ws, size_t ws_size,
                              hipStream_t stream) {
  const float* x       = (const float*)d_in[0];
  const float* context = (const float*)d_in[1];
  const void*  mask    = d_in[2];
  const float* g_x     = (const float*)d_in[3];
  const float* null_kv = (const float*)d_in[4];
  const float* Wq      = (const float*)d_in[5];
  const float* Wkv     = (const float*)d_in[6];
  const float* Wo      = (const float*)d_in[7];
  const float* g_out   = (const float*)d_in[8];

  char* w = (char*)d_ws;
  size_t off = 0;
  auto alloc = [&](size_t bytes) { size_t o = off; off = (off + bytes + 255) & ~(size_t)255; return o; };

  u16* WqT    = (u16*)(w + alloc((size_t)512 * 512 * 2));
  u16* WkvT   = (u16*)(w + alloc((size_t)1024 * 512 * 2));
  u16* WoT    = (u16*)(w + alloc((size_t)512 * 512 * 2));
  float* mp   = (float*)(w + alloc((size_t)2 * MPAD * 4));
  u16* KVt    = (u16*)(w + alloc((size_t)16 * 66 * 8192 * 2));
  u16* qb     = (u16*)(w + alloc((size_t)8192 * 512 * 2));
  u16* aO     = (u16*)(w + alloc((size_t)8192 * 512 * 2));   // (unused now; keeps layout)
  size_t xn_off = alloc((size_t)8192 * 512 * 2);   // 8 MB
  size_t cb_off = alloc((size_t)8192 * 512 * 2);   // 8 MB (contiguous with xn)
  float* lbb  = (float*)(w + alloc((size_t)2 * GRPS * 64 * 4));
  u16* xn   = (u16*)(w + xn_off);
  u16* cb   = (u16*)(w + cb_off);
  // Opart (2*1024*2048 u32 = 16.78 MB) aliases xn+cb exactly (dead after proj GEMMs)
  u32* Opart = (u32*)(w + xn_off);
  (void)aO;

  // prep: maskpad | W transposes | ln(x)+cast(ctx) | KVt fill — one launch
  prep_all<<<7217, 256, 0, stream>>>(mask, mp, Wq, Wkv, Wo, WqT, WkvT, WoT,
                                     x, g_x, xn, (const float4*)context, cb,
                                     null_kv, KVt);

  // q-proj + kv-proj in one launch (768 blocks = 3/CU, XCD-swizzled)
  gemm_qkv<<<768, 256, 0, stream>>>(xn, WqT, qb, cb, WkvT, KVt);

  // barrier-free split-K flash attention (S=2)
  attn_kernel<<<512, 256, 0, stream>>>(qb, KVt, mp, Opart, lbb);

  // fused tail: combine -> staged-B o-proj -> final LN (512 blocks = 2/CU)
  tail3<<<512, 256, 0, stream>>>(Opart, lbb, WoT, g_out, (float*)d_out);
}

// Round 16
// 227.046 us; speedup vs baseline: 1.0193x; 1.0193x over previous
//
#include <hip/hip_runtime.h>
#include <cfloat>

typedef unsigned short u16;
typedef unsigned int u32;
typedef __bf16 v8bf16 __attribute__((ext_vector_type(8)));
typedef float v4f32 __attribute__((ext_vector_type(4)));
typedef float v16f32 __attribute__((ext_vector_type(16)));

#define MPAD 4224            // 4097 keys padded to 66*64
// sqrt(1/8) * sqrt(log2(e)) : folds head-scale AND base-2 softmax into q and k
#define QKS 0.42466090f
#define GRPS 1024            // waves per split: (16 bh) * (16 qt) * (4 w)

__device__ __forceinline__ u16 f2bf(float f) {
  union { float f; u32 u; } v; v.f = f;
  u32 u = v.u;
  u32 r = (u + 0x7FFFu + ((u >> 16) & 1u)) >> 16;
  return (u16)r;
}

// pack two f32 -> one u32 holding (bf16(hi)<<16)|bf16(lo), truncating
__device__ __forceinline__ u32 pkbf(float lo, float hi) {
  union { float f; u32 u; } a, c;
  a.f = lo; c.f = hi;
  return __builtin_amdgcn_perm(c.u, a.u, 0x07060302);
}

__device__ __forceinline__ float asf(u32 u) {
  union { u32 u; float f; } v; v.u = u; return v.f;
}

// exp2 + row-sum + bf16 pack for one q-group (both kc halves).
// Half-wave exchange via v_permlane32_swap_b32 (R1/R8-proven).
__device__ __forceinline__ void exppack2(v16f32& sA, v16f32& sB, float& lst,
                                         v8bf16 pf[4]) {
  float rsum = 0.f;
#pragma unroll
  for (int i = 0; i < 16; i++) { float p = __builtin_amdgcn_exp2f(sA[i]); sA[i] = p; rsum += p; }
#pragma unroll
  for (int i = 0; i < 16; i++) { float p = __builtin_amdgcn_exp2f(sB[i]); sB[i] = p; rsum += p; }
  float a2 = rsum, b2 = rsum;
  asm("v_permlane32_swap_b32 %0, %1" : "+v"(a2), "+v"(b2));
  lst += a2 + b2;   // own + partner (lane^32)
#pragma unroll
  for (int kc = 0; kc < 2; kc++) {
    v16f32& s = kc ? sB : sA;
#pragma unroll
    for (int s16 = 0; s16 < 2; s16++) {
      u32 w0 = pkbf(s[s16 * 8 + 0], s[s16 * 8 + 1]);
      u32 w1 = pkbf(s[s16 * 8 + 2], s[s16 * 8 + 3]);
      u32 w2 = pkbf(s[s16 * 8 + 4], s[s16 * 8 + 5]);
      u32 w3 = pkbf(s[s16 * 8 + 6], s[s16 * 8 + 7]);
      asm("v_permlane32_swap_b32 %0, %1" : "+v"(w0), "+v"(w2));
      asm("v_permlane32_swap_b32 %0, %1" : "+v"(w1), "+v"(w3));
      union { u32 u[4]; v8bf16 v; } pu;
      pu.u[0] = w0; pu.u[1] = w1; pu.u[2] = w2; pu.u[3] = w3;
      pf[kc * 2 + s16] = pu.v;
    }
  }
}

// ================= prep_all: 4 independent prep stages in ONE launch ===============
__global__ __launch_bounds__(256) void prep_all(
    const void* __restrict__ mask, float* __restrict__ mp,
    const float* __restrict__ Wq, const float* __restrict__ Wkv,
    const float* __restrict__ Wo, u16* __restrict__ WqT,
    u16* __restrict__ WkvT, u16* __restrict__ WoT,
    const float* __restrict__ x, const float* __restrict__ g,
    u16* __restrict__ xn, const float4* __restrict__ ctx, u16* __restrict__ cb,
    const float* __restrict__ nullkv, u16* __restrict__ KVt) {
  int bb = blockIdx.x;
  int tid = threadIdx.x;
  if (bb < 33) {
    __shared__ int sflag;
    if (tid == 0) sflag = 0;
    __syncthreads();
    const unsigned char* mb = (const unsigned char*)mask;
    int loc = 0;
#pragma unroll
    for (int k = 0; k < 32; k++) {
      int i = tid * 32 + k;
      if ((i & 3) && mb[i]) loc = 1;
    }
    if (loc) sflag = 1;
    __syncthreads();
    int isbyte = sflag;
    int i = bb * 256 + tid;
    if (i >= 2 * MPAD) return;
    int b = i / MPAD, p = i - b * MPAD;
    float v;
    if (p == 0) v = 0.f;
    else if (p <= 4096) {
      int j = b * 4096 + (p - 1);
      int on = isbyte ? (((const unsigned char*)mask)[j] != 0)
                      : (((const int*)mask)[j] != 0);
      v = on ? 0.f : -1e38f;
    } else v = -1e38f;
    mp[i] = v;
  } else if (bb < 1057) {
    __shared__ float tile[32][33];
    int t = bb - 33;
    const float* in; u16* out; int N; float scale; int base;
    if (t < 256)      { in = Wq;  out = WqT;  N = 512;  scale = QKS; base = t; }
    else if (t < 768) { in = Wkv; out = WkvT; N = 1024; scale = 1.f; base = t - 256; }
    else              { in = Wo;  out = WoT;  N = 512;  scale = 1.f; base = t - 768; }
    const int K = 512;
    int ntiles = N >> 5;
    int bx = base % ntiles, by = base / ntiles;
    int n0 = bx * 32, k0 = by * 32;
    int c = tid & 31, r8 = tid >> 5;
#pragma unroll
    for (int i = 0; i < 4; i++) {
      int r = r8 + i * 8;
      tile[r][c] = in[(size_t)(k0 + r) * N + n0 + c];
    }
    __syncthreads();
#pragma unroll
    for (int i = 0; i < 4; i++) {
      int r = r8 + i * 8;
      out[(size_t)(n0 + r) * K + k0 + c] = f2bf(tile[c][r] * scale);
    }
  } else if (bb < 7201) {
    int local = bb - 1057;
    if (local < 2048) {
      int lane = tid & 63, w = tid >> 6;
      int row = local * 4 + w;
      const float* p = x + (size_t)row * 512 + lane * 8;
      float4 f0 = *(const float4*)p;
      float4 f1 = *(const float4*)(p + 4);
      float v[8] = {f0.x, f0.y, f0.z, f0.w, f1.x, f1.y, f1.z, f1.w};
      float sum = 0.f, sq = 0.f;
#pragma unroll
      for (int i = 0; i < 8; i++) { sum += v[i]; sq += v[i] * v[i]; }
#pragma unroll
      for (int m = 1; m < 64; m <<= 1) { sum += __shfl_xor(sum, m); sq += __shfl_xor(sq, m); }
      float mean = sum * (1.f / 512.f);
      float var = sq * (1.f / 512.f) - mean * mean;
      float rstd = rsqrtf(var + 1e-5f);
      const float* gp = g + lane * 8;
      u16 o[8];
#pragma unroll
      for (int i = 0; i < 8; i++) o[i] = f2bf((v[i] - mean) * rstd * gp[i]);
      *(uint4*)&xn[(size_t)row * 512 + lane * 8] = *(uint4*)o;
    } else {
      int i = (local - 2048) * 256 + tid;
      float4 f = ctx[i];
      u16 o[4] = {f2bf(f.x), f2bf(f.y), f2bf(f.z), f2bf(f.w)};
      *(uint2*)&cb[(size_t)i * 4] = *(uint2*)o;
    }
  } else {
    int bh = bb - 7201;
    size_t tb64 = ((size_t)bh * 66 + 64) * 8192;
    uint4 z = make_uint4(0, 0, 0, 0);
    for (int i = tid; i < 2048; i += 256)
      *(uint4*)&KVt[tb64 + (size_t)i * 8] = z;
    size_t tb0 = (size_t)bh * 66 * 8192;
    if (tid < 64) {
      int d = tid;
      KVt[tb0 + (size_t)(d >> 3) * 512 + (d & 7)] = f2bf(nullkv[d] * QKS);
      KVt[tb0 + 4096 + (size_t)d * 8] = f2bf(nullkv[64 + d]);
    }
  }
}

// ---------------- bf16 MFMA GEMM core (m97-structure, R8-proven) -------------------
__device__ __forceinline__ void gemm_core(const u16* __restrict__ A,
    const u16* __restrict__ Bt, u16* __restrict__ outb,
    u16* __restrict__ KVt, int Ncols, int mode, int bidx,
    u16* As /*128*32*/, u16* Bs /*128*32*/) {
  int tiles_n = Ncols >> 7;
  int n0 = (bidx % tiles_n) * 128;
  int m0 = (bidx / tiles_n) * 128;
  int tid = threadIdx.x;
  int lane = tid & 63, w = tid >> 6, quad = lane >> 4, l15 = lane & 15;
  int wr = w >> 1, wc = w & 1;
  int srow = tid >> 2, scol = (tid & 3) * 8;
  v4f32 acc[4][4];
#pragma unroll
  for (int i = 0; i < 4; i++)
#pragma unroll
    for (int j = 0; j < 4; j++) acc[i][j] = (v4f32){0.f, 0.f, 0.f, 0.f};

  for (int k0 = 0; k0 < 512; k0 += 32) {
    __syncthreads();
    __builtin_amdgcn_global_load_lds((const u32*)&A[(size_t)(m0 + srow) * 512 + k0 + scol],
                                     (u32*)&As[tid * 8], 16, 0, 0);
    __builtin_amdgcn_global_load_lds((const u32*)&A[(size_t)(m0 + 64 + srow) * 512 + k0 + scol],
                                     (u32*)&As[64 * 32 + tid * 8], 16, 0, 0);
    __builtin_amdgcn_global_load_lds((const u32*)&Bt[(size_t)(n0 + srow) * 512 + k0 + scol],
                                     (u32*)&Bs[tid * 8], 16, 0, 0);
    __builtin_amdgcn_global_load_lds((const u32*)&Bt[(size_t)(n0 + 64 + srow) * 512 + k0 + scol],
                                     (u32*)&Bs[64 * 32 + tid * 8], 16, 0, 0);
    __syncthreads();
    v8bf16 af[4], bf[4];
#pragma unroll
    for (int i = 0; i < 4; i++)
      af[i] = *(const v8bf16*)&As[(wr * 64 + i * 16 + l15) * 32 + quad * 8];
#pragma unroll
    for (int j = 0; j < 4; j++)
      bf[j] = *(const v8bf16*)&Bs[(wc * 64 + j * 16 + l15) * 32 + quad * 8];
#pragma unroll
    for (int i = 0; i < 4; i++)
#pragma unroll
      for (int j = 0; j < 4; j++)
        acc[i][j] = __builtin_amdgcn_mfma_f32_16x16x32_bf16(af[i], bf[j], acc[i][j], 0, 0, 0);
  }
#pragma unroll
  for (int i = 0; i < 4; i++) {
    int rbase = m0 + wr * 64 + i * 16 + quad * 4;
#pragma unroll
    for (int j = 0; j < 4; j++) {
      int col = n0 + wc * 64 + j * 16 + l15;
#pragma unroll
      for (int r = 0; r < 4; r++) {
        float v = acc[i][j][r];
        int row = rbase + r;
        if (mode == 0) {
          outb[(size_t)row * 512 + col] = f2bf(v);
        } else {
          int b2 = row >> 12, mr = row & 4095;
          int kk = mr + 1, kt = kk >> 6, kl = kk & 63;
          int kvsel = col >> 9, hh = (col >> 6) & 7, d = col & 63;
          size_t tb = ((size_t)(b2 * 8 + hh) * 66 + kt) * 8192;
          if (kvsel == 0) {
            int chunk = (((d >> 4) * 2 + ((d >> 3) & 1)) * 2 + (kl >> 5)) * 32 + (kl & 31);
            KVt[tb + (size_t)chunk * 8 + (d & 7)] = f2bf(v * QKS);
          } else {
            int chunk = (((kl >> 4) * 2 + ((kl >> 3) & 1)) * 2 + (d >> 5)) * 32 + (d & 31);
            KVt[tb + 4096 + (size_t)chunk * 8 + (kl & 7)] = f2bf(v);
          }
        }
      }
    }
  }
}

// q-proj (bid 0..255) and kv-proj (bid 256..767) in ONE launch, XCD-swizzled
// (R14 A/B: swizzle neutral, kept as harmless)
__global__ __launch_bounds__(256) void gemm_qkv(const u16* __restrict__ xn,
    const u16* __restrict__ WqT, u16* __restrict__ qb,
    const u16* __restrict__ cb, const u16* __restrict__ WkvT,
    u16* __restrict__ KVt) {
  __shared__ __attribute__((aligned(16))) u16 As[128 * 32];
  __shared__ __attribute__((aligned(16))) u16 Bs[128 * 32];
  int obid = blockIdx.x;
  int bb = (obid & 7) * 96 + (obid >> 3);   // bijective over 0..767
  if (bb < 256) gemm_core(xn, WqT, qb, nullptr, 512, 0, bb, As, Bs);
  else          gemm_core(cb, WkvT, nullptr, KVt, 1024, 1, bb - 256, As, Bs);
}

// ---------------- flash attention v16 (R10-proven: R8 body + setprio) ----------------
__global__ __launch_bounds__(256, 2) void attn_kernel(const u16* __restrict__ q,
    const u16* __restrict__ KVt, const float* __restrict__ maskbias,
    u32* __restrict__ Opart, float* __restrict__ lbuf) {
  int obid = blockIdx.x;
  int bid = (obid & 7) * 64 + (obid >> 3);   // 512 = 8 XCDs * 64: bijective
  int qt = bid & 15, bhs = bid >> 4;
  int s_p = bhs & 1, bh = bhs >> 1;
  int b = bh >> 3, hh = bh & 7;
  int tid = threadIdx.x, lane = tid & 63, w = tid >> 6;
  int m31 = lane & 31, h = (lane >> 5) & 1;
  int grp = (bh * 16 + qt) * 4 + w;
  int q0 = qt * 256 + w * 64;

  v8bf16 qf[2][4];
#pragma unroll
  for (int qg = 0; qg < 2; qg++) {
    const u16* qp = q + (size_t)(b * 4096 + q0 + qg * 32 + m31) * 512 + hh * 64 + h * 8;
#pragma unroll
    for (int ks = 0; ks < 4; ks++) qf[qg][ks] = *(const v8bf16*)&qp[ks * 16];
  }

  v16f32 acc[2][2];
#pragma unroll
  for (int qg = 0; qg < 2; qg++)
#pragma unroll
    for (int db = 0; db < 2; db++)
#pragma unroll
      for (int i = 0; i < 16; i++) acc[qg][db][i] = 0.f;
  float l_st[2] = {0.f, 0.f};

  const u16* kvb = KVt + (size_t)bh * 66 * 8192 + (size_t)(h * 64 + m31) * 8;
  const float* mg = maskbias + b * MPAD;
  int kt0 = s_p * 33;

  for (int kt = kt0; kt < kt0 + 33; ++kt) {
    const u16* tb = kvb + (size_t)kt * 8192;
    v8bf16 kf[4][2];
#pragma unroll
    for (int ks = 0; ks < 4; ks++)
#pragma unroll
      for (int kc = 0; kc < 2; kc++)
        kf[ks][kc] = *(const v8bf16*)&tb[ks * 1024 + kc * 256];
    v16f32 bias_s[2];
#pragma unroll
    for (int kc = 0; kc < 2; kc++)
#pragma unroll
      for (int gg = 0; gg < 4; gg++) {
        float4 bv = *(const float4*)&mg[kt * 64 + kc * 32 + gg * 8 + h * 4];
        bias_s[kc][gg * 4 + 0] = bv.x;
        bias_s[kc][gg * 4 + 1] = bv.y;
        bias_s[kc][gg * 4 + 2] = bv.z;
        bias_s[kc][gg * 4 + 3] = bv.w;
      }

    v8bf16 pf[2][4];
    {
      v16f32 s0 = bias_s[0], s1 = bias_s[1];
      __builtin_amdgcn_s_setprio(1);
#pragma unroll
      for (int ks = 0; ks < 4; ks++) {
        s0 = __builtin_amdgcn_mfma_f32_32x32x16_bf16(kf[ks][0], qf[0][ks], s0, 0, 0, 0);
        s1 = __builtin_amdgcn_mfma_f32_32x32x16_bf16(kf[ks][1], qf[0][ks], s1, 0, 0, 0);
      }
      __builtin_amdgcn_s_setprio(0);
      exppack2(s0, s1, l_st[0], pf[0]);
    }
    __builtin_amdgcn_s_setprio(1);
#pragma unroll
    for (int ks = 0; ks < 4; ks++) {
      bias_s[0] = __builtin_amdgcn_mfma_f32_32x32x16_bf16(kf[ks][0], qf[1][ks], bias_s[0], 0, 0, 0);
      bias_s[1] = __builtin_amdgcn_mfma_f32_32x32x16_bf16(kf[ks][1], qf[1][ks], bias_s[1], 0, 0, 0);
    }
    __builtin_amdgcn_s_setprio(0);
    exppack2(bias_s[0], bias_s[1], l_st[1], pf[1]);

    v8bf16 vf[4][2];
#pragma unroll
    for (int jb = 0; jb < 4; jb++)
#pragma unroll
      for (int db = 0; db < 2; db++)
        vf[jb][db] = *(const v8bf16*)&tb[4096 + jb * 1024 + db * 256];

    __builtin_amdgcn_s_setprio(1);
#pragma unroll
    for (int qg = 0; qg < 2; qg++)
#pragma unroll
      for (int jb = 0; jb < 4; jb++)
#pragma unroll
        for (int db = 0; db < 2; db++)
          acc[qg][db] = __builtin_amdgcn_mfma_f32_32x32x16_bf16(vf[jb][db], pf[qg][jb], acc[qg][db], 0, 0, 0);
    __builtin_amdgcn_s_setprio(0);
  }

  size_t ob = (size_t)(s_p * GRPS + grp) * 2048;
#pragma unroll
  for (int qg = 0; qg < 2; qg++)
#pragma unroll
    for (int db = 0; db < 2; db++)
#pragma unroll
      for (int rp = 0; rp < 8; rp++)
        Opart[ob + qg * 1024 + (size_t)(db * 8 + rp) * 64 + lane] =
            pkbf(acc[qg][db][2 * rp], acc[qg][db][2 * rp + 1]);
  if (h == 0) {
    lbuf[(size_t)(s_p * GRPS + grp) * 64 + m31] = l_st[0];
    lbuf[(size_t)(s_p * GRPS + grp) * 64 + 32 + m31] = l_st[1];
  }
}

// ============ tail3 v2 (R12/R14-proven best): 256 blocks x 32-row panels ============
// bid = ((b*16+qt)*4+w)*2+qg.
// Stage 1: 8 combine units -> As[32][520]. Stage 2: waves 2x2, B staged per k-step
// via global_load_lds (4-wave shared). Stage 3: LN via l15-shfl + 512B LDS table.
__global__ __launch_bounds__(256) void tail3(const u32* __restrict__ Opart,
    const float* __restrict__ lbuf, const u16* __restrict__ WoT,
    const float* __restrict__ g, float* __restrict__ out) {
  __shared__ __attribute__((aligned(16))) u16 As[32 * 520];   // 33280 B
  __shared__ __attribute__((aligned(16))) u16 Bs[512 * 32];   // 32768 B
  __shared__ float part[2][32][2];                            // 512 B
  int bid = blockIdx.x;
  int tid = threadIdx.x;
  int w4 = tid >> 6, lane = tid & 63;
  int m31 = lane & 31, h = (lane >> 5) & 1;
  int qg = bid & 1, w = (bid >> 1) & 3, qt = (bid >> 3) & 15, b = bid >> 7;
  size_t rowbase = (size_t)b * 4096 + qt * 256 + w * 64 + qg * 32;

  // ---- stage 1: combine 8 units into As (each wave does 2)
#pragma unroll
  for (int i = 0; i < 2; i++) {
    int hh = i * 4 + w4;
    int grp = (b * 8 + hh) * 64 + qt * 4 + w;
    float l0 = lbuf[(size_t)grp * 64 + qg * 32 + m31];
    float l1 = lbuf[(size_t)(GRPS + grp) * 64 + qg * 32 + m31];
    float inv = 1.f / (l0 + l1);
#pragma unroll
    for (int db = 0; db < 2; db++)
#pragma unroll
      for (int rp = 0; rp < 8; rp++) {
        u32 a = Opart[(size_t)grp * 2048 + qg * 1024 + (db * 8 + rp) * 64 + lane];
        u32 c = Opart[(size_t)(GRPS + grp) * 2048 + qg * 1024 + (db * 8 + rp) * 64 + lane];
        float fe = (asf(a << 16) + asf(c << 16)) * inv;
        float fo = (asf(a & 0xFFFF0000u) + asf(c & 0xFFFF0000u)) * inv;
        int reg = 2 * rp;
        int d0 = (reg & 3) + 8 * (reg >> 2) + 4 * h + 32 * db;
        *(u32*)&As[m31 * 520 + hh * 64 + d0] = pkbf(fe, fo);
      }
  }

  // ---- stage 2: GEMM (32x512) = As x WoT^T; wave (rg,cg) = 16 rows x 256 cols
  int quad = lane >> 4, l15 = lane & 15;
  int rg = w4 & 1, cg = w4 >> 1;
  int srow = tid >> 2, scol = (tid & 3) * 8;
  v4f32 acc[16];
#pragma unroll
  for (int j = 0; j < 16; j++) acc[j] = (v4f32){0.f, 0.f, 0.f, 0.f};

  for (int k0 = 0; k0 < 512; k0 += 32) {
    __syncthreads();   // first iter: also guards As writes
#pragma unroll
    for (int v = 0; v < 8; v++)
      __builtin_amdgcn_global_load_lds((const u32*)&WoT[(size_t)(v * 64 + srow) * 512 + k0 + scol],
                                       (u32*)&Bs[(size_t)v * 2048 + tid * 8], 16, 0, 0);
    __syncthreads();
    v8bf16 af = *(const v8bf16*)&As[(rg * 16 + l15) * 520 + k0 + quad * 8];
#pragma unroll
    for (int j = 0; j < 16; j++) {
      v8bf16 bf = *(const v8bf16*)&Bs[(cg * 256 + j * 16 + l15) * 32 + quad * 8];
      acc[j] = __builtin_amdgcn_mfma_f32_16x16x32_bf16(af, bf, acc[j], 0, 0, 0);
    }
  }

  // ---- stage 3: LN. lane holds rows rg*16+quad*4+r, cols cg*256 + j*16+l15.
  float rs[4] = {0.f, 0.f, 0.f, 0.f}, sq[4] = {0.f, 0.f, 0.f, 0.f};
#pragma unroll
  for (int j = 0; j < 16; j++)
#pragma unroll
    for (int r = 0; r < 4; r++) { float v = acc[j][r]; rs[r] += v; sq[r] += v * v; }
#pragma unroll
  for (int m = 1; m < 16; m <<= 1)
#pragma unroll
    for (int r = 0; r < 4; r++) { rs[r] += __shfl_xor(rs[r], m); sq[r] += __shfl_xor(sq[r], m); }
  if (l15 == 0) {
#pragma unroll
    for (int r = 0; r < 4; r++) {
      part[cg][rg * 16 + quad * 4 + r][0] = rs[r];
      part[cg][rg * 16 + quad * 4 + r][1] = sq[r];
    }
  }
  __syncthreads();
  float mean[4], rstd[4];
#pragma unroll
  for (int r = 0; r < 4; r++) {
    int rl = rg * 16 + quad * 4 + r;
    float trs = part[0][rl][0] + part[1][rl][0];
    float tsq = part[0][rl][1] + part[1][rl][1];
    mean[r] = trs * (1.f / 512.f);
    float var = tsq * (1.f / 512.f) - mean[r] * mean[r];
    rstd[r] = rsqrtf(var + 1e-5f);
  }
#pragma unroll
  for (int j = 0; j < 16; j++) {
    float gv = g[cg * 256 + j * 16 + l15];
#pragma unroll
    for (int r = 0; r < 4; r++) {
      size_t row = rowbase + rg * 16 + quad * 4 + r;
      out[row * 512 + cg * 256 + j * 16 + l15] = (acc[j][r] - mean[r]) * rstd[r] * gv;
    }
  }
}

// =======================================================================
extern "C" void kernel_launch(void* const* d_in, const int* in_sizes, int n_in,
                              void* d_out, int out_size, void* d_ws, size_t ws_size,
                              hipStream_t stream) {
  const float* x       = (const float*)d_in[0];
  const float* context = (const float*)d_in[1];
  const void*  mask    = d_in[2];
  const float* g_x     = (const float*)d_in[3];
  const float* null_kv = (const float*)d_in[4];
  const float* Wq      = (const float*)d_in[5];
  const float* Wkv     = (const float*)d_in[6];
  const float* Wo      = (const float*)d_in[7];
  const float* g_out   = (const float*)d_in[8];

  char* w = (char*)d_ws;
  size_t off = 0;
  auto alloc = [&](size_t bytes) { size_t o = off; off = (off + bytes + 255) & ~(size_t)255; return o; };

  u16* WqT    = (u16*)(w + alloc((size_t)512 * 512 * 2));
  u16* WkvT   = (u16*)(w + alloc((size_t)1024 * 512 * 2));
  u16* WoT    = (u16*)(w + alloc((size_t)512 * 512 * 2));
  float* mp   = (float*)(w + alloc((size_t)2 * MPAD * 4));
  u16* KVt    = (u16*)(w + alloc((size_t)16 * 66 * 8192 * 2));
  u16* qb     = (u16*)(w + alloc((size_t)8192 * 512 * 2));
  u16* aO     = (u16*)(w + alloc((size_t)8192 * 512 * 2));   // (unused now; keeps layout)
  size_t xn_off = alloc((size_t)8192 * 512 * 2);   // 8 MB
  size_t cb_off = alloc((size_t)8192 * 512 * 2);   // 8 MB (contiguous with xn)
  float* lbb  = (float*)(w + alloc((size_t)2 * GRPS * 64 * 4));
  u16* xn   = (u16*)(w + xn_off);
  u16* cb   = (u16*)(w + cb_off);
  // Opart (2*1024*2048 u32 = 16.78 MB) aliases xn+cb exactly (dead after proj GEMMs)
  u32* Opart = (u32*)(w + xn_off);
  (void)aO;

  // prep: maskpad | W transposes | ln(x)+cast(ctx) | KVt fill — one launch
  prep_all<<<7217, 256, 0, stream>>>(mask, mp, Wq, Wkv, Wo, WqT, WkvT, WoT,
                                     x, g_x, xn, (const float4*)context, cb,
                                     null_kv, KVt);

  // q-proj + kv-proj in one launch (768 blocks = 3/CU, XCD-swizzled)
  gemm_qkv<<<768, 256, 0, stream>>>(xn, WqT, qb, cb, WkvT, KVt);

  // barrier-free split-K flash attention (S=2)
  attn_kernel<<<512, 256, 0, stream>>>(qb, KVt, mp, Opart, lbb);

  // fused tail: combine -> staged-B o-proj -> final LN (256 blocks, proven best)
  tail3<<<256, 256, 0, stream>>>(Opart, lbb, WoT, g_out, (float*)d_out);
}